// Round 12
// baseline (1786.311 us; speedup 1.0000x reference)
//
#include <hip/hip_runtime.h>
#include <hip/hip_bf16.h>
#include <math.h>

namespace {
constexpr int V = 32000, D = 1024, L = 8, H = 16, T = 128, F = 2816, DH = 64;
constexpr float EPS = 1e-5f;
constexpr float SCALE = 0.125f; // 1/sqrt(DH)
constexpr int QKVN = 3 * D;     // 3072
constexpr int GUN  = 2 * F;     // 5632
constexpr int NP_Q = 4;         // QKV split-K chunks (CH=256)
constexpr int NP_O = 8;         // O-proj chunks (CH=128)
constexpr int NP_G = 4;         // GU chunks (CH=256)
constexpr int NP_D = 11;        // Wd chunks (K=2816 = 11*256)
constexpr int NBLK = 512;       // 2 blocks/CU guaranteed via __launch_bounds__(512,4)
constexpr int NSUB = 16;
constexpr int QUOTA = NBLK / NSUB;   // 32 arrivals per sub-counter
constexpr int SLOT_STRIDE = 544;     // uints per barrier slot (16 subs*32 + master@512)
constexpr int NBAR = 8;              // barriers per layer
}

typedef __attribute__((ext_vector_type(8))) short short8;
typedef __attribute__((ext_vector_type(4))) float f32x4;

__device__ __forceinline__ unsigned short f2bf(float x) {
    union { float f; unsigned u; } v; v.f = x;
    unsigned r = v.u + 0x7FFFu + ((v.u >> 16) & 1u);
    return (unsigned short)(r >> 16);
}

// ---- grid barrier: 2-level arrive, RELAXED spin, one acquire at exit ----
// (round-7 proven correct). Each slot used ONCE per call; memset'd per call.
__device__ __forceinline__ void gridbar(unsigned* slot) {
    __syncthreads();
    if (threadIdx.x == 0) {
        unsigned* subp = slot + (blockIdx.x & (NSUB - 1)) * 32;
        unsigned* mast = slot + 512;
        unsigned prev = __hip_atomic_fetch_add(subp, 1u, __ATOMIC_RELEASE,
                                               __HIP_MEMORY_SCOPE_AGENT);
        if (prev == QUOTA - 1)
            __hip_atomic_fetch_add(mast, 1u, __ATOMIC_RELEASE, __HIP_MEMORY_SCOPE_AGENT);
        while (__hip_atomic_load(mast, __ATOMIC_RELAXED, __HIP_MEMORY_SCOPE_AGENT)
               != (unsigned)NSUB)
            __builtin_amdgcn_s_sleep(2);
        (void)__hip_atomic_load(mast, __ATOMIC_ACQUIRE, __HIP_MEMORY_SCOPE_AGENT);
    }
    __syncthreads();
}

// ---------------- Embedding gather + RoPE tables (fused) ----------------
__global__ void embed_rope_kernel(const int* __restrict__ ids, const float* __restrict__ emb,
                                  float* __restrict__ X,
                                  float* __restrict__ cosT, float* __restrict__ sinT) {
    int t = blockIdx.x, tid = threadIdx.x;
    int id = ids[t];
    ((float4*)(X + (size_t)t * D))[tid] = ((const float4*)(emb + (size_t)id * D))[tid];
    if (tid < 32) {
        float inv = powf(10000.0f, -(2.0f * (float)tid) / (float)DH);
        float ang = (float)t * inv;
        cosT[t * 32 + tid] = cosf(ang);
        sinT[t * 32 + tid] = sinf(ang);
    }
}

// ---------------- wave-level units (round-7 proven) ----------------

// rmsnorm row t (one wave): X[t,:] += sum partials; Y = norm(X)*w (bf16)
__device__ __forceinline__ void rmsnorm_unit(int t, int lane, float* __restrict__ X,
                                             const float* __restrict__ P, int np,
                                             const float* __restrict__ w,
                                             unsigned short* __restrict__ Y) {
    const int base = t * D + lane * 16;
    float4 xv[4];
    #pragma unroll
    for (int q = 0; q < 4; ++q) xv[q] = *(const float4*)(X + base + q * 4);
    for (int c = 0; c < np; ++c) {
        const float* pb = P + (size_t)c * T * D + base;
        #pragma unroll
        for (int q = 0; q < 4; ++q) {
            float4 pv = *(const float4*)(pb + q * 4);
            xv[q].x += pv.x; xv[q].y += pv.y; xv[q].z += pv.z; xv[q].w += pv.w;
        }
    }
    if (np) {
        #pragma unroll
        for (int q = 0; q < 4; ++q) *(float4*)(X + base + q * 4) = xv[q];
    }
    float s = 0.f;
    #pragma unroll
    for (int q = 0; q < 4; ++q)
        s += xv[q].x * xv[q].x + xv[q].y * xv[q].y + xv[q].z * xv[q].z + xv[q].w * xv[q].w;
    for (int o = 32; o >= 1; o >>= 1) s += __shfl_xor(s, o);
    float r = rsqrtf(s / (float)D + EPS);
    #pragma unroll
    for (int q = 0; q < 4; ++q) {
        float4 wv = *(const float4*)(w + lane * 16 + q * 4);
        ushort4 y;
        y.x = f2bf(xv[q].x * r * wv.x); y.y = f2bf(xv[q].y * r * wv.y);
        y.z = f2bf(xv[q].z * r * wv.z); y.w = f2bf(xv[q].w * r * wv.w);
        *(ushort4*)(Y + base + q * 4) = y;
    }
}

// QKV partial reduce + RoPE: one wave = row t, 256-dim quarter qn
__device__ __forceinline__ void rope_unit(int t, int qn, int lane,
                                          const float* __restrict__ P,
                                          const float* __restrict__ cosT,
                                          const float* __restrict__ sinT,
                                          float* __restrict__ Qr, float* __restrict__ Kr,
                                          float* __restrict__ Vr) {
    const int d0 = qn * 256 + lane * 4;
    float4 q = {0.f, 0.f, 0.f, 0.f}, k = q, v = q;
    #pragma unroll
    for (int c = 0; c < NP_Q; ++c) {
        const float* base = P + ((size_t)c * T + t) * QKVN;
        float4 a = *(const float4*)(base + d0);
        float4 b = *(const float4*)(base + D + d0);
        float4 w = *(const float4*)(base + 2 * D + d0);
        q.x += a.x; q.y += a.y; q.z += a.z; q.w += a.w;
        k.x += b.x; k.y += b.y; k.z += b.z; k.w += b.w;
        v.x += w.x; v.y += w.y; v.z += w.z; v.w += w.w;
    }
    float4 c4 = *(const float4*)(cosT + t * 32 + (d0 & 31));
    float4 s4 = *(const float4*)(sinT + t * 32 + (d0 & 31));
    float sgn = (d0 & 32) ? 1.f : -1.f;
    float4 qp, kp;
    qp.x = __shfl_xor(q.x, 8); qp.y = __shfl_xor(q.y, 8);
    qp.z = __shfl_xor(q.z, 8); qp.w = __shfl_xor(q.w, 8);
    kp.x = __shfl_xor(k.x, 8); kp.y = __shfl_xor(k.y, 8);
    kp.z = __shfl_xor(k.z, 8); kp.w = __shfl_xor(k.w, 8);
    float4 qo, ko;
    qo.x = q.x * c4.x + sgn * qp.x * s4.x; qo.y = q.y * c4.y + sgn * qp.y * s4.y;
    qo.z = q.z * c4.z + sgn * qp.z * s4.z; qo.w = q.w * c4.w + sgn * qp.w * s4.w;
    ko.x = k.x * c4.x + sgn * kp.x * s4.x; ko.y = k.y * c4.y + sgn * kp.y * s4.y;
    ko.z = k.z * c4.z + sgn * kp.z * s4.z; ko.w = k.w * c4.w + sgn * kp.w * s4.w;
    *(float4*)(Qr + (size_t)t * D + d0) = qo;
    *(float4*)(Kr + (size_t)t * D + d0) = ko;
    *(float4*)(Vr + (size_t)t * D + d0) = v;
}

// one (t,h) attention unit, wave-local; fixed-trip unrolled PV (round-11)
__device__ __forceinline__ void attn_unit(int t, int h, int lane,
                                          const float* __restrict__ Qr,
                                          const float* __restrict__ Kr,
                                          const float* __restrict__ Vr,
                                          unsigned short* __restrict__ AO,
                                          float* q, float* p) {
    q[lane] = Qr[(size_t)t * D + h * DH + lane];
    int j0 = lane, j1 = lane + 64;
    const float* kr0 = Kr + (size_t)j0 * D + h * DH;
    const float* kr1 = Kr + (size_t)j1 * D + h * DH;
    float s0 = 0.f, s1 = 0.f;
    #pragma unroll
    for (int d = 0; d < DH; ++d) {
        float qd = q[d];
        s0 = fmaf(qd, kr0[d], s0);
        s1 = fmaf(qd, kr1[d], s1);
    }
    s0 = (j0 <= t) ? s0 * SCALE : -1e30f;
    s1 = (j1 <= t) ? s1 * SCALE : -1e30f;
    float m = fmaxf(s0, s1);
    for (int o = 32; o >= 1; o >>= 1) m = fmaxf(m, __shfl_xor(m, o));
    float e0 = (j0 <= t) ? __expf(s0 - m) : 0.f;
    float e1 = (j1 <= t) ? __expf(s1 - m) : 0.f;
    float sum = e0 + e1;
    for (int o = 32; o >= 1; o >>= 1) sum += __shfl_xor(sum, o);
    float inv = 1.f / sum;
    p[j0] = e0 * inv;   // p[j] = 0 for j > t -> fixed-trip PV exact
    p[j1] = e1 * inv;
    const float* vcol = Vr + h * DH + lane;
    float a0 = 0.f, a1 = 0.f, a2 = 0.f, a3 = 0.f;
    #pragma unroll
    for (int j = 0; j < T; j += 4) {
        a0 = fmaf(p[j],     vcol[(size_t)(j)     * D], a0);
        a1 = fmaf(p[j + 1], vcol[(size_t)(j + 1) * D], a1);
        a2 = fmaf(p[j + 2], vcol[(size_t)(j + 2) * D], a2);
        a3 = fmaf(p[j + 3], vcol[(size_t)(j + 3) * D], a3);
    }
    AO[(size_t)t * D + h * DH + lane] = f2bf((a0 + a1) + (a2 + a3));
}

// silu reduce: wave = (row t, 256-wide f-chunk fq)
__device__ __forceinline__ void silu_unit(int t, int fq, int lane,
                                          const float* __restrict__ P3,
                                          unsigned short* __restrict__ Gact) {
    const int f0 = fq * 256 + lane * 4;
    float4 g = {0.f, 0.f, 0.f, 0.f}, u = g;
    #pragma unroll
    for (int c = 0; c < NP_G; ++c) {
        const float* base = P3 + ((size_t)c * T + t) * GUN;
        float4 a = *(const float4*)(base + f0);
        float4 b = *(const float4*)(base + F + f0);
        g.x += a.x; g.y += a.y; g.z += a.z; g.w += a.w;
        u.x += b.x; u.y += b.y; u.z += b.z; u.w += b.w;
    }
    ushort4 y;
    y.x = f2bf(g.x / (1.f + __expf(-g.x)) * u.x);
    y.y = f2bf(g.y / (1.f + __expf(-g.y)) * u.y);
    y.z = f2bf(g.z / (1.f + __expf(-g.z)) * u.z);
    y.w = f2bf(g.w / (1.f + __expf(-g.w)) * u.w);
    *(ushort4*)(Gact + (size_t)t * F + f0) = y;
}

// ---------------- block-level GEMM unit (round-11 proven, 512 threads) ----------------
// Wave = (M-half mh) x (col-group cg). 16 cols x 64 rows per wave (4 frags).
// Weight tile staged fp32->bf16 via LDS (256B coalesced), double-buffered.
template<int CH>
__device__ __forceinline__ void gemm_unit(unsigned short* Bst,
                                          const unsigned short* __restrict__ A, int lda,
                                          const float* __restrict__ W, int ldw,
                                          int n0, int k0,
                                          float* __restrict__ outP, int ldo, int outcol0) {
    constexpr int STAGES = CH / 128;
    constexpr int LSTR = 136;
    const int tid = threadIdx.x;
    const int wave = tid >> 6, lane = tid & 63;
    const int cg = wave & 3, mh = wave >> 2;
    const int sc = tid & 63;
    const int so = tid >> 6;  // 0..7
    const float* wCol = W + (size_t)k0 * ldw + n0 + sc;
    unsigned short* wp = Bst + sc * LSTR;
    const int lrow = lane & 15;
    const int lqo = lane >> 4;
    const unsigned short* aB = A + (size_t)(mh * 64 + lrow) * lda + k0 + lqo * 8;
    const unsigned short* bRd = Bst + (cg * 16 + lrow) * LSTR + lqo * 8;
    f32x4 acc[4] = {};
    float pre[16];
    auto ldst = [&](int s) {
        #pragma unroll
        for (int p = 0; p < 2; ++p) {
            const float* src = wCol + (size_t)(s * 128 + (so * 2 + p) * 8) * ldw;
            #pragma unroll
            for (int j = 0; j < 8; ++j) pre[p * 8 + j] = src[(size_t)j * ldw];
        }
    };
    auto wrst = [&](int buf) {
        #pragma unroll
        for (int p = 0; p < 2; ++p) {
            short8 bv;
            #pragma unroll
            for (int j = 0; j < 8; ++j) bv[j] = (short)f2bf(pre[p * 8 + j]);
            *(short8*)(wp + buf * (64 * LSTR) + (so * 2 + p) * 8) = bv;
        }
    };
    ldst(0);
    wrst(0);
    __syncthreads();
    #pragma unroll
    for (int s = 0; s < STAGES; ++s) {
        if (s + 1 < STAGES) ldst(s + 1);
        const unsigned short* rd = bRd + (s & 1) * (64 * LSTR);
        #pragma unroll
        for (int ks = 0; ks < 4; ++ks) {
            short8 b = *(const short8*)(rd + ks * 32);
            #pragma unroll
            for (int mf = 0; mf < 4; ++mf) {
                short8 a = *(const short8*)(aB + (size_t)(mf * 16) * lda + s * 128 + ks * 32);
                acc[mf] = __builtin_amdgcn_mfma_f32_16x16x32_bf16(a, b, acc[mf], 0, 0, 0);
            }
        }
        if (s + 1 < STAGES) {
            __syncthreads();
            wrst((s + 1) & 1);
            __syncthreads();
        }
    }
    const int col = outcol0 + cg * 16 + lrow;
    #pragma unroll
    for (int mf = 0; mf < 4; ++mf) {
        int r0 = mh * 64 + mf * 16 + lqo * 4;
        #pragma unroll
        for (int r = 0; r < 4; ++r)
            outP[(size_t)(r0 + r) * ldo + col] = acc[mf][r];
    }
}

// ---------------- per-layer persistent megakernel (9 phases, 8 barriers) ----------------
__global__ __launch_bounds__(512, 4)
void layer_kernel(const float* __restrict__ wq, const float* __restrict__ wk,
                  const float* __restrict__ wv, const float* __restrict__ wo,
                  const float* __restrict__ wg, const float* __restrict__ wu,
                  const float* __restrict__ wd,
                  const float* __restrict__ anorm, const float* __restrict__ fnorm,
                  float* __restrict__ X,
                  float* __restrict__ P0, float* __restrict__ P1,
                  float* __restrict__ P2, float* __restrict__ P3,
                  float* __restrict__ Qr, float* __restrict__ Kr, float* __restrict__ Vr,
                  const float* __restrict__ cosT, const float* __restrict__ sinT,
                  unsigned short* __restrict__ Hn, unsigned short* __restrict__ AO,
                  unsigned short* __restrict__ Gact,
                  unsigned* bar, int np_prev) {
    __shared__ unsigned short Bst[2 * 64 * 136];  // 34816 B
    __shared__ float qs[8][64];
    __shared__ float ps[8][128];
    const int wave = threadIdx.x >> 6, lane = threadIdx.x & 63;
    const int blk = blockIdx.x;
    const int gw = blk * 8 + wave;  // 0..4095

    // A: X += prev Wd partials; Hn = rmsnorm(X)*anorm   (128 wave units)
    if (gw < T) rmsnorm_unit(gw, lane, X, P2, np_prev, anorm, Hn);
    gridbar(bar + 0 * SLOT_STRIDE);
    // B: QKV -> P0 partials (192 block units: z(3) x kc(4) x ct(16))
    if (blk < 192) {
        int z = blk / 64, rem = blk % 64, kc = rem / 16, ct = rem % 16;
        const float* W = z == 0 ? wq : (z == 1 ? wk : wv);
        gemm_unit<256>(Bst, Hn, D, W, D, ct * 64, kc * 256,
                       P0 + (size_t)kc * T * QKVN, QKVN, z * D + ct * 64);
    }
    gridbar(bar + 1 * SLOT_STRIDE);
    // C: reduce + RoPE (512 wave units: t x 4 quarters)
    if (gw < 512) rope_unit(gw >> 2, gw & 3, lane, P0, cosT, sinT, Qr, Kr, Vr);
    gridbar(bar + 2 * SLOT_STRIDE);
    // D: attention (2048 (t,h) wave units)
    if (gw < 2048) attn_unit(gw >> 4, gw & 15, lane, Qr, Kr, Vr, AO, qs[wave], ps[wave]);
    gridbar(bar + 3 * SLOT_STRIDE);
    // E: O-proj -> P1 (128 block units: kc(8) x ct(16), CH=128)
    if (blk < 128) {
        int kc = blk / 16, ct = blk % 16;
        gemm_unit<128>(Bst, AO, D, wo, D, ct * 64, kc * 128,
                       P1 + (size_t)kc * T * D, D, ct * 64);
    }
    gridbar(bar + 4 * SLOT_STRIDE);
    // F: X += P1; Hn = rmsnorm(X)*fnorm (128 wave units)
    if (gw < T) rmsnorm_unit(gw, lane, X, P1, NP_O, fnorm, Hn);
    gridbar(bar + 5 * SLOT_STRIDE);
    // G: GU -> P3 (352 block units: z(2) x kc(4) x ct(44))
    if (blk < 352) {
        int z = blk / 176, rem = blk % 176, kc = rem / 44, ct = rem % 44;
        const float* W = z ? wu : wg;
        gemm_unit<256>(Bst, Hn, D, W, F, ct * 64, kc * 256,
                       P3 + (size_t)kc * T * GUN, GUN, z * F + ct * 64);
    }
    gridbar(bar + 6 * SLOT_STRIDE);
    // H: silu reduce -> Gact (1408 wave units: fq(11) x t(128))
    if (gw < 1408) silu_unit(gw & 127, gw >> 7, lane, P3, Gact);
    gridbar(bar + 7 * SLOT_STRIDE);
    // I: Wd -> P2 partials (176 block units: kc(11) x ct(16)), consumed next launch
    if (blk < 176) {
        int kc = blk / 16, ct = blk % 16;
        gemm_unit<256>(Bst, Gact, F, wd, D, ct * 64, kc * 256,
                       P2 + (size_t)kc * T * D, D, ct * 64);
    }
}

// ---------------- final norm of last token (adds last Wd partials) ----------------
__global__ void final_norm_kernel(float* __restrict__ X, const float* __restrict__ P2,
                                  const float* __restrict__ w, float* __restrict__ xl) {
    int tid = threadIdx.x;
    float4 xv = ((float4*)(X + (size_t)(T - 1) * D))[tid];
    #pragma unroll
    for (int c = 0; c < NP_D; ++c) {
        float4 pv = ((const float4*)(P2 + ((size_t)c * T + (T - 1)) * D))[tid];
        xv.x += pv.x; xv.y += pv.y; xv.z += pv.z; xv.w += pv.w;
    }
    float s = xv.x * xv.x + xv.y * xv.y + xv.z * xv.z + xv.w * xv.w;
    for (int o = 32; o >= 1; o >>= 1) s += __shfl_xor(s, o);
    __shared__ float red[4];
    if ((tid & 63) == 0) red[tid >> 6] = s;
    __syncthreads();
    float tot = red[0] + red[1] + red[2] + red[3];
    float r = rsqrtf(tot / (float)D + EPS);
    float4 wv = ((const float4*)w)[tid];
    float4 y;
    y.x = xv.x * r * wv.x; y.y = xv.y * r * wv.y;
    y.z = xv.z * r * wv.z; y.w = xv.w * r * wv.w;
    ((float4*)(xl))[tid] = y;
}

// ---------------- logits: out[v] = emb[v,:] . xl ----------------
__global__ void logits_kernel(const float* __restrict__ emb, const float* __restrict__ xl,
                              float* __restrict__ out) {
    __shared__ float x[D];
    int tid = threadIdx.x;
    ((float4*)x)[tid] = ((const float4*)xl)[tid];
    __syncthreads();
    int row = blockIdx.x * 4 + (tid >> 6);
    int lane = tid & 63;
    const float4* e4 = (const float4*)(emb + (size_t)row * D);
    const float4* x4 = (const float4*)x;
    float s = 0.f;
    #pragma unroll
    for (int k = lane; k < D / 4; k += 64) {
        float4 ev = e4[k], xv = x4[k];
        s += ev.x * xv.x + ev.y * xv.y + ev.z * xv.z + ev.w * xv.w;
    }
    for (int o = 32; o >= 1; o >>= 1) s += __shfl_xor(s, o);
    if (lane == 0) out[row] = s;
}

extern "C" void kernel_launch(void* const* d_in, const int* in_sizes, int n_in,
                              void* d_out, int out_size, void* d_ws, size_t ws_size,
                              hipStream_t stream) {
    const int*   ids = (const int*)d_in[0];
    const float* emb = (const float*)d_in[1];
    const float* Wq  = (const float*)d_in[2];
    const float* Wk  = (const float*)d_in[3];
    const float* Wv  = (const float*)d_in[4];
    const float* Wo  = (const float*)d_in[5];
    const float* Wg  = (const float*)d_in[6];
    const float* Wu  = (const float*)d_in[7];
    const float* Wd  = (const float*)d_in[8];
    const float* attn_norm = (const float*)d_in[9];
    const float* ffn_norm  = (const float*)d_in[10];
    const float* norm_out  = (const float*)d_in[11];
    float* out = (float*)d_out;

    size_t off = 0;
    auto alloc = [&](size_t bytes) {
        void* p = (char*)d_ws + off;
        off += (bytes + 255) & ~(size_t)255;
        return p;
    };
    unsigned*       bar   = (unsigned*)alloc((size_t)L * NBAR * SLOT_STRIDE * 4);
    float*          X     = (float*)alloc((size_t)T * D * 4);
    float*          P0    = (float*)alloc((size_t)NP_Q * T * QKVN * 4);
    float*          P1    = (float*)alloc((size_t)NP_O * T * D * 4);
    float*          P2    = (float*)alloc((size_t)NP_D * T * D * 4);
    float*          P3    = (float*)alloc((size_t)NP_G * T * GUN * 4);
    float*          Qr    = (float*)alloc((size_t)T * D * 4);
    float*          Kr    = (float*)alloc((size_t)T * D * 4);
    float*          Vr    = (float*)alloc((size_t)T * D * 4);
    float*          cosT  = (float*)alloc((size_t)T * 32 * 4);
    float*          sinT  = (float*)alloc((size_t)T * 32 * 4);
    float*          xl    = (float*)alloc((size_t)D * 4);
    unsigned short* Hn_bf = (unsigned short*)alloc((size_t)T * D * 2);
    unsigned short* AO_bf = (unsigned short*)alloc((size_t)T * D * 2);
    unsigned short* Gact  = (unsigned short*)alloc((size_t)T * F * 2);
    (void)ws_size;

    // barrier slots zeroed once per call (captured in graph, replayed each time)
    hipMemsetAsync(bar, 0, (size_t)L * NBAR * SLOT_STRIDE * 4, stream);
    embed_rope_kernel<<<T, 256, 0, stream>>>(ids, emb, X, cosT, sinT);

    for (int l = 0; l < L; ++l) {
        layer_kernel<<<NBLK, 512, 0, stream>>>(
            Wq + (size_t)l * D * D, Wk + (size_t)l * D * D,
            Wv + (size_t)l * D * D, Wo + (size_t)l * D * D,
            Wg + (size_t)l * D * F, Wu + (size_t)l * D * F,
            Wd + (size_t)l * F * D,
            attn_norm + (size_t)l * D, ffn_norm + (size_t)l * D,
            X, P0, P1, P2, P3, Qr, Kr, Vr, cosT, sinT,
            Hn_bf, AO_bf, Gact,
            bar + (size_t)l * NBAR * SLOT_STRIDE, l == 0 ? 0 : NP_D);
    }

    final_norm_kernel<<<1, 256, 0, stream>>>(X, P2, norm_out, xl);
    logits_kernel<<<V / 4, 256, 0, stream>>>(emb, xl, out);
}

// Round 13
// 783.625 us; speedup vs baseline: 2.2795x; 2.2795x over previous
//
#include <hip/hip_runtime.h>
#include <hip/hip_bf16.h>
#include <math.h>

namespace {
constexpr int V = 32000, D = 1024, L = 8, H = 16, T = 128, F = 2816, DH = 64;
constexpr float EPS = 1e-5f;
constexpr float SCALE = 0.125f; // 1/sqrt(DH)
constexpr int QKVN = 3 * D;     // 3072
constexpr int GUN  = 2 * F;     // 5632
constexpr int NP_Q = 4;         // QKV split-K chunks (CH=256)
constexpr int NP_O = 8;         // O-proj chunks (CH=128)
constexpr int NP_G = 4;         // GU chunks (CH=256)
constexpr int NP_D = 11;        // Wd chunks (K=2816 = 11*256)
}

typedef __attribute__((ext_vector_type(8))) short short8;
typedef __attribute__((ext_vector_type(4))) float f32x4;

__device__ __forceinline__ unsigned short f2bf(float x) {
    union { float f; unsigned u; } v; v.f = x;
    unsigned r = v.u + 0x7FFFu + ((v.u >> 16) & 1u);
    return (unsigned short)(r >> 16);
}

// ---------------- Embedding gather + RoPE tables (fused) ----------------
__global__ void embed_rope_kernel(const int* __restrict__ ids, const float* __restrict__ emb,
                                  float* __restrict__ X,
                                  float* __restrict__ cosT, float* __restrict__ sinT) {
    int t = blockIdx.x, tid = threadIdx.x;
    int id = ids[t];
    ((float4*)(X + (size_t)t * D))[tid] = ((const float4*)(emb + (size_t)id * D))[tid];
    if (tid < 32) {
        float inv = powf(10000.0f, -(2.0f * (float)tid) / (float)DH);
        float ang = (float)t * inv;
        cosT[t * 32 + tid] = cosf(ang);
        sinT[t * 32 + tid] = sinf(ang);
    }
}

// ---------------- RMSNorm + unrolled partial-sum residual update ----------------
template<int NP, bool BF16OUT>
__launch_bounds__(256)
__global__ void rmsnorm_sum_kernel(float* __restrict__ X, const float* __restrict__ P,
                                   const float* __restrict__ w, void* __restrict__ Y) {
    int t = blockIdx.x, tid = threadIdx.x;
    float4 xv = ((float4*)(X + (size_t)t * D))[tid];
    #pragma unroll
    for (int c = 0; c < NP; ++c) {
        float4 pv = ((const float4*)(P + ((size_t)c * T + t) * D))[tid];
        xv.x += pv.x; xv.y += pv.y; xv.z += pv.z; xv.w += pv.w;
    }
    if (NP) ((float4*)(X + (size_t)t * D))[tid] = xv;
    float s = xv.x * xv.x + xv.y * xv.y + xv.z * xv.z + xv.w * xv.w;
    for (int o = 32; o >= 1; o >>= 1) s += __shfl_xor(s, o);
    __shared__ float red[4];
    if ((tid & 63) == 0) red[tid >> 6] = s;
    __syncthreads();
    float tot = red[0] + red[1] + red[2] + red[3];
    float r = rsqrtf(tot / (float)D + EPS);
    float4 wv = ((const float4*)w)[tid];
    if (BF16OUT) {
        ushort4 y;
        y.x = f2bf(xv.x * r * wv.x); y.y = f2bf(xv.y * r * wv.y);
        y.z = f2bf(xv.z * r * wv.z); y.w = f2bf(xv.w * r * wv.w);
        ((ushort4*)((unsigned short*)Y + (size_t)t * D))[tid] = y;
    } else {
        float4 y;
        y.x = xv.x * r * wv.x; y.y = xv.y * r * wv.y;
        y.z = xv.z * r * wv.z; y.w = xv.w * r * wv.w;
        ((float4*)((float*)Y + (size_t)t * D))[tid] = y;
    }
}

// ---------------- 64-col staged MFMA GEMM, fp32 [K][N] weights, split-K ----------------
// (round-11 proven) 512 threads / 8 waves: wave = (M-half mh) x (col-group cg).
template<int CH>
__launch_bounds__(512)
__global__ void gemm64_kernel(const unsigned short* __restrict__ A, int lda,
                              const float* __restrict__ W0, const float* __restrict__ W1,
                              const float* __restrict__ W2, int ldw,
                              float* __restrict__ out, int ldo, int zColOff,
                              size_t chunkStride) {
    constexpr int STAGES = CH / 128;
    constexpr int LSTR = 136;
    __shared__ unsigned short Bst[2][64 * LSTR];
    const float* W = blockIdx.z == 0 ? W0 : (blockIdx.z == 1 ? W1 : W2);
    const int tid = threadIdx.x;
    const int wave = tid >> 6, lane = tid & 63;
    const int cg = wave & 3, mh = wave >> 2;
    const int n0 = blockIdx.x * 64;
    const int k0 = blockIdx.y * CH;
    const int sc = tid & 63;
    const int so = tid >> 6;  // 0..7
    const float* wCol = W + (size_t)k0 * ldw + n0 + sc;
    unsigned short* wp = &Bst[0][sc * LSTR];
    const int lrow = lane & 15;
    const int lqo = lane >> 4;
    const unsigned short* aB = A + (size_t)(mh * 64 + lrow) * lda + k0 + lqo * 8;
    const unsigned short* bRd = &Bst[0][(cg * 16 + lrow) * LSTR + lqo * 8];
    f32x4 acc[4] = {};
    float pre[16];
    auto ldst = [&](int s) {
        #pragma unroll
        for (int p = 0; p < 2; ++p) {
            const float* src = wCol + (size_t)(s * 128 + (so * 2 + p) * 8) * ldw;
            #pragma unroll
            for (int j = 0; j < 8; ++j) pre[p * 8 + j] = src[(size_t)j * ldw];
        }
    };
    auto wrst = [&](int buf) {
        #pragma unroll
        for (int p = 0; p < 2; ++p) {
            short8 bv;
            #pragma unroll
            for (int j = 0; j < 8; ++j) bv[j] = (short)f2bf(pre[p * 8 + j]);
            *(short8*)(wp + buf * (64 * LSTR) + (so * 2 + p) * 8) = bv;
        }
    };
    ldst(0);
    wrst(0);
    __syncthreads();
    #pragma unroll
    for (int s = 0; s < STAGES; ++s) {
        if (s + 1 < STAGES) ldst(s + 1);
        const unsigned short* rd = bRd + (s & 1) * (64 * LSTR);
        #pragma unroll
        for (int ks = 0; ks < 4; ++ks) {
            short8 b = *(const short8*)(rd + ks * 32);
            #pragma unroll
            for (int mf = 0; mf < 4; ++mf) {
                short8 a = *(const short8*)(aB + (size_t)(mf * 16) * lda + s * 128 + ks * 32);
                acc[mf] = __builtin_amdgcn_mfma_f32_16x16x32_bf16(a, b, acc[mf], 0, 0, 0);
            }
        }
        if (s + 1 < STAGES) {
            __syncthreads();
            wrst((s + 1) & 1);
            __syncthreads();
        }
    }
    const int col = zColOff * blockIdx.z + n0 + cg * 16 + lrow;
    float* op = out + blockIdx.y * chunkStride;
    #pragma unroll
    for (int mf = 0; mf < 4; ++mf) {
        int r0 = mh * 64 + mf * 16 + lqo * 4;
        #pragma unroll
        for (int r = 0; r < 4; ++r)
            op[(size_t)(r0 + r) * ldo + col] = acc[mf][r];
    }
}

// ---------------- Fused attention: partial-reduce + RoPE + softmax + PV ----------------
// Block (half, h): 512 threads. Stages roped K, V, roped Q for head h into LDS
// (reducing the NP_Q partials once per block), then 8 waves x 8 queries compute
// scores/softmax/PV entirely from LDS. Replaces rope_reduce + attn kernels.
__launch_bounds__(512)
__global__ void attn_fused_kernel(const float* __restrict__ P0,
                                  const float* __restrict__ cosT,
                                  const float* __restrict__ sinT,
                                  unsigned short* __restrict__ AO) {
    constexpr int KP = 68;  // row pad: 64 + 4 floats
    __shared__ float Ks[128][KP];
    __shared__ float Vs[128][KP];
    __shared__ float Qs[64][KP];
    __shared__ float ps[8][128];
    const int half = blockIdx.x;        // 0: queries 0..63, 1: queries 64..127
    const int h = blockIdx.y;
    const int tid = threadIdx.x;
    const int wave = tid >> 6, lane = tid & 63;
    const int hoff = h * DH;
    const int q0 = half * 64;
    const int rows = half ? 128 : 64;   // keys needed

    // --- stage K (reduce partials + rope) ---
    for (int it = 0; it < rows / 16; ++it) {       // rows*32/512
        int idx = it * 512 + tid;
        int j = idx >> 5, d = idx & 31;
        float ka = 0.f, kb = 0.f;
        #pragma unroll
        for (int c = 0; c < NP_Q; ++c) {
            const float* b = P0 + ((size_t)c * T + j) * QKVN + D + hoff;
            ka += b[d]; kb += b[d + 32];
        }
        float cc = cosT[j * 32 + d], sn = sinT[j * 32 + d];
        Ks[j][d] = ka * cc - kb * sn;
        Ks[j][d + 32] = kb * cc + ka * sn;
    }
    // --- stage V (reduce partials), float4 ---
    for (int it = 0; it < rows / 32; ++it) {       // rows*16/512
        int idx = it * 512 + tid;
        int j = idx >> 4, d4 = idx & 15;
        float4 v = {0.f, 0.f, 0.f, 0.f};
        #pragma unroll
        for (int c = 0; c < NP_Q; ++c) {
            float4 pv = *(const float4*)(P0 + ((size_t)c * T + j) * QKVN + 2 * D + hoff + d4 * 4);
            v.x += pv.x; v.y += pv.y; v.z += pv.z; v.w += pv.w;
        }
        *(float4*)&Vs[j][d4 * 4] = v;
    }
    // --- stage Q (reduce partials + rope), queries q0..q0+63 ---
    for (int it = 0; it < 4; ++it) {               // 64*32/512
        int idx = it * 512 + tid;
        int tq = idx >> 5, d = idx & 31;
        int t = q0 + tq;
        float qa = 0.f, qb = 0.f;
        #pragma unroll
        for (int c = 0; c < NP_Q; ++c) {
            const float* b = P0 + ((size_t)c * T + t) * QKVN + hoff;
            qa += b[d]; qb += b[d + 32];
        }
        float cc = cosT[t * 32 + d], sn = sinT[t * 32 + d];
        Qs[tq][d] = qa * cc - qb * sn;
        Qs[tq][d + 32] = qb * cc + qa * sn;
    }
    __syncthreads();

    // --- compute: wave handles queries tq = wave*8 .. +7 ---
    for (int qi = 0; qi < 8; ++qi) {
        int tq = wave * 8 + qi;
        int t = q0 + tq;
        const float4* qrow = (const float4*)Qs[tq];
        // scores: lane = key j0 (and j1 = lane+64 if half)
        int j0 = lane;
        float s0 = 0.f, s1 = 0.f;
        const float4* k0 = (const float4*)Ks[j0];
        #pragma unroll
        for (int d4 = 0; d4 < 16; ++d4) {
            float4 qv = qrow[d4], kv = k0[d4];
            s0 += qv.x * kv.x + qv.y * kv.y + qv.z * kv.z + qv.w * kv.w;
        }
        if (half) {
            const float4* k1 = (const float4*)Ks[lane + 64];
            #pragma unroll
            for (int d4 = 0; d4 < 16; ++d4) {
                float4 qv = qrow[d4], kv = k1[d4];
                s1 += qv.x * kv.x + qv.y * kv.y + qv.z * kv.z + qv.w * kv.w;
            }
        }
        bool v0 = (j0 <= t), v1 = half && (lane + 64 <= t);
        s0 = v0 ? s0 * SCALE : -1e30f;
        s1 = v1 ? s1 * SCALE : -1e30f;
        float m = fmaxf(s0, s1);
        for (int o = 32; o >= 1; o >>= 1) m = fmaxf(m, __shfl_xor(m, o));
        float e0 = v0 ? __expf(s0 - m) : 0.f;
        float e1 = v1 ? __expf(s1 - m) : 0.f;
        float sum = e0 + e1;
        for (int o = 32; o >= 1; o >>= 1) sum += __shfl_xor(sum, o);
        float inv = 1.f / sum;
        ps[wave][j0] = e0 * inv;
        if (half) ps[wave][lane + 64] = e1 * inv;
        // PV: lane = (j-group jg) x (d-quarter d4); reduce jg via shfl
        int jg = lane >> 4, d4 = lane & 15;
        int jspan = rows >> 2;  // 16 or 32
        float4 acc = {0.f, 0.f, 0.f, 0.f};
        const float* pw = ps[wave];
        for (int j = jg * jspan; j < (jg + 1) * jspan; ++j) {
            float pj = pw[j];
            float4 vv = *(const float4*)&Vs[j][d4 * 4];
            acc.x = fmaf(pj, vv.x, acc.x);
            acc.y = fmaf(pj, vv.y, acc.y);
            acc.z = fmaf(pj, vv.z, acc.z);
            acc.w = fmaf(pj, vv.w, acc.w);
        }
        #pragma unroll
        for (int o = 16; o <= 32; o <<= 1) {
            acc.x += __shfl_xor(acc.x, o);
            acc.y += __shfl_xor(acc.y, o);
            acc.z += __shfl_xor(acc.z, o);
            acc.w += __shfl_xor(acc.w, o);
        }
        if (jg == 0) {
            ushort4 y;
            y.x = f2bf(acc.x); y.y = f2bf(acc.y);
            y.z = f2bf(acc.z); y.w = f2bf(acc.w);
            *(ushort4*)(AO + (size_t)t * D + hoff + d4 * 4) = y;
        }
    }
}

// ---------------- GU partial reduce + silu(g)*u -> Gact bf16 [T][F] ----------------
__launch_bounds__(256)
__global__ void silu_reduce_kernel(const float* __restrict__ P,
                                   unsigned short* __restrict__ Gact) {
    int t = blockIdx.y;
    int f = blockIdx.x * 256 + threadIdx.x;
    float g = 0.f, u = 0.f;
    #pragma unroll
    for (int c = 0; c < NP_G; ++c) {
        const float* base = P + ((size_t)c * T + t) * GUN;
        g += base[f];
        u += base[F + f];
    }
    Gact[(size_t)t * F + f] = f2bf(g / (1.f + __expf(-g)) * u);
}

// ---------------- logits: out[v] = emb[v,:] . xl ----------------
__global__ void logits_kernel(const float* __restrict__ emb, const float* __restrict__ xl,
                              float* __restrict__ out) {
    __shared__ float x[D];
    int tid = threadIdx.x;
    ((float4*)x)[tid] = ((const float4*)xl)[tid];
    __syncthreads();
    int row = blockIdx.x * 4 + (tid >> 6);
    int lane = tid & 63;
    const float4* e4 = (const float4*)(emb + (size_t)row * D);
    const float4* x4 = (const float4*)x;
    float s = 0.f;
    #pragma unroll
    for (int k = lane; k < D / 4; k += 64) {
        float4 ev = e4[k], xv = x4[k];
        s += ev.x * xv.x + ev.y * xv.y + ev.z * xv.z + ev.w * xv.w;
    }
    for (int o = 32; o >= 1; o >>= 1) s += __shfl_xor(s, o);
    if (lane == 0) out[row] = s;
}

extern "C" void kernel_launch(void* const* d_in, const int* in_sizes, int n_in,
                              void* d_out, int out_size, void* d_ws, size_t ws_size,
                              hipStream_t stream) {
    const int*   ids = (const int*)d_in[0];
    const float* emb = (const float*)d_in[1];
    const float* Wq  = (const float*)d_in[2];
    const float* Wk  = (const float*)d_in[3];
    const float* Wv  = (const float*)d_in[4];
    const float* Wo  = (const float*)d_in[5];
    const float* Wg  = (const float*)d_in[6];
    const float* Wu  = (const float*)d_in[7];
    const float* Wd  = (const float*)d_in[8];
    const float* attn_norm = (const float*)d_in[9];
    const float* ffn_norm  = (const float*)d_in[10];
    const float* norm_out  = (const float*)d_in[11];
    float* out = (float*)d_out;

    size_t off = 0;
    auto alloc = [&](size_t bytes) {
        void* p = (char*)d_ws + off;
        off += (bytes + 255) & ~(size_t)255;
        return p;
    };
    float*          X     = (float*)alloc((size_t)T * D * 4);
    float*          P0    = (float*)alloc((size_t)NP_Q * T * QKVN * 4);  // QKV partials
    float*          P1    = (float*)alloc((size_t)NP_O * T * D * 4);     // O-proj partials
    float*          P2    = (float*)alloc((size_t)NP_D * T * D * 4);     // Wd partials
    float*          P3    = (float*)alloc((size_t)NP_G * T * GUN * 4);   // GU partials
    float*          cosT  = (float*)alloc((size_t)T * 32 * 4);
    float*          sinT  = (float*)alloc((size_t)T * 32 * 4);
    float*          xl    = (float*)alloc((size_t)D * 4);
    unsigned short* Hn_bf = (unsigned short*)alloc((size_t)T * D * 2);
    unsigned short* AO_bf = (unsigned short*)alloc((size_t)T * D * 2);
    unsigned short* Gact  = (unsigned short*)alloc((size_t)T * F * 2);
    (void)ws_size;

    embed_rope_kernel<<<T, 256, 0, stream>>>(ids, emb, X, cosT, sinT);

    for (int l = 0; l < L; ++l) {
        const float* wq = Wq + (size_t)l * D * D;
        const float* wk = Wk + (size_t)l * D * D;
        const float* wv = Wv + (size_t)l * D * D;
        const float* wo = Wo + (size_t)l * D * D;
        const float* wg = Wg + (size_t)l * D * F;
        const float* wu = Wu + (size_t)l * D * F;
        const float* wd = Wd + (size_t)l * F * D;

        // X += prev Wd partials; Hn = rmsnorm(X)*attn_norm (bf16)
        if (l == 0)
            rmsnorm_sum_kernel<0, true><<<T, 256, 0, stream>>>(
                X, P2, attn_norm + (size_t)l * D, Hn_bf);
        else
            rmsnorm_sum_kernel<NP_D, true><<<T, 256, 0, stream>>>(
                X, P2, attn_norm + (size_t)l * D, Hn_bf);
        // QKV partials: 64-col, K=1024 split 4x256, z in {q,k,v} -> 192 blocks x 8 waves
        gemm64_kernel<256><<<dim3(D / 64, NP_Q, 3), 512, 0, stream>>>(
            Hn_bf, D, wq, wk, wv, D, P0, QKVN, D, (size_t)T * QKVN);
        // fused reduce+rope+attention: 32 blocks (2 halves x 16 heads)
        attn_fused_kernel<<<dim3(2, H), 512, 0, stream>>>(P0, cosT, sinT, AO_bf);
        // O-proj partials: K=1024 split 8x128 -> 128 blocks x 8 waves
        gemm64_kernel<128><<<dim3(D / 64, NP_O, 1), 512, 0, stream>>>(
            AO_bf, D, wo, wo, wo, D, P1, D, 0, (size_t)T * D);
        rmsnorm_sum_kernel<NP_O, true><<<T, 256, 0, stream>>>(
            X, P1, ffn_norm + (size_t)l * D, Hn_bf);
        // GU partials: K=1024 split 4x256, z in {g,u} -> 352 blocks x 8 waves
        gemm64_kernel<256><<<dim3(F / 64, NP_G, 2), 512, 0, stream>>>(
            Hn_bf, D, wg, wu, wu, F, P3, GUN, F, (size_t)T * GUN);
        silu_reduce_kernel<<<dim3(F / 256, T), 256, 0, stream>>>(P3, Gact);
        // Wd partials: K=2816 split 11x256 -> 176 blocks x 8 waves
        gemm64_kernel<256><<<dim3(D / 64, NP_D, 1), 512, 0, stream>>>(
            Gact, F, wd, wd, wd, D, P2, D, 0, (size_t)T * D);
    }

    // final: xl = rmsnorm(X[127] + sum P2[c][127]) * norm_out (fp32)
    rmsnorm_sum_kernel<NP_D, false><<<1, 256, 0, stream>>>(
        X + (size_t)(T - 1) * D, P2 + (size_t)(T - 1) * D, norm_out, xl);
    logits_kernel<<<V / 4, 256, 0, stream>>>(emb, xl, out);
}

// Round 14
// 668.595 us; speedup vs baseline: 2.6717x; 1.1720x over previous
//
#include <hip/hip_runtime.h>
#include <hip/hip_bf16.h>
#include <math.h>

namespace {
constexpr int V = 32000, D = 1024, L = 8, H = 16, T = 128, F = 2816, DH = 64;
constexpr float EPS = 1e-5f;
constexpr float SCALE = 0.125f; // 1/sqrt(DH)
constexpr int QKVN = 3 * D;     // 3072
constexpr int GUN  = 2 * F;     // 5632
constexpr int NP_Q = 8;         // QKV split-K chunks (CH=128)
constexpr int NP_O = 8;         // O-proj chunks (CH=128)
constexpr int NP_G = 8;         // GU chunks (CH=128)
constexpr int NP_D = 22;        // Wd chunks (K=2816 = 22*128)
}

typedef __attribute__((ext_vector_type(8))) short short8;
typedef __attribute__((ext_vector_type(4))) float f32x4;

__device__ __forceinline__ unsigned short f2bf(float x) {
    union { float f; unsigned u; } v; v.f = x;
    unsigned r = v.u + 0x7FFFu + ((v.u >> 16) & 1u);
    return (unsigned short)(r >> 16);
}

// ---------------- Embedding gather + RoPE tables (fused) ----------------
__global__ void embed_rope_kernel(const int* __restrict__ ids, const float* __restrict__ emb,
                                  float* __restrict__ X,
                                  float* __restrict__ cosT, float* __restrict__ sinT) {
    int t = blockIdx.x, tid = threadIdx.x;
    int id = ids[t];
    ((float4*)(X + (size_t)t * D))[tid] = ((const float4*)(emb + (size_t)id * D))[tid];
    if (tid < 32) {
        float inv = powf(10000.0f, -(2.0f * (float)tid) / (float)DH);
        float ang = (float)t * inv;
        cosT[t * 32 + tid] = cosf(ang);
        sinT[t * 32 + tid] = sinf(ang);
    }
}

// ---------------- RMSNorm + unrolled partial-sum residual update ----------------
template<int NP, bool BF16OUT>
__launch_bounds__(256)
__global__ void rmsnorm_sum_kernel(float* __restrict__ X, const float* __restrict__ P,
                                   const float* __restrict__ w, void* __restrict__ Y) {
    int t = blockIdx.x, tid = threadIdx.x;
    float4 xv = ((float4*)(X + (size_t)t * D))[tid];
    #pragma unroll
    for (int c = 0; c < NP; ++c) {
        float4 pv = ((const float4*)(P + ((size_t)c * T + t) * D))[tid];
        xv.x += pv.x; xv.y += pv.y; xv.z += pv.z; xv.w += pv.w;
    }
    if (NP) ((float4*)(X + (size_t)t * D))[tid] = xv;
    float s = xv.x * xv.x + xv.y * xv.y + xv.z * xv.z + xv.w * xv.w;
    for (int o = 32; o >= 1; o >>= 1) s += __shfl_xor(s, o);
    __shared__ float red[4];
    if ((tid & 63) == 0) red[tid >> 6] = s;
    __syncthreads();
    float tot = red[0] + red[1] + red[2] + red[3];
    float r = rsqrtf(tot / (float)D + EPS);
    float4 wv = ((const float4*)w)[tid];
    if (BF16OUT) {
        ushort4 y;
        y.x = f2bf(xv.x * r * wv.x); y.y = f2bf(xv.y * r * wv.y);
        y.z = f2bf(xv.z * r * wv.z); y.w = f2bf(xv.w * r * wv.w);
        ((ushort4*)((unsigned short*)Y + (size_t)t * D))[tid] = y;
    } else {
        float4 y;
        y.x = xv.x * r * wv.x; y.y = xv.y * r * wv.y;
        y.z = xv.z * r * wv.z; y.w = xv.w * r * wv.w;
        ((float4*)((float*)Y + (size_t)t * D))[tid] = y;
    }
}

// ---------------- 64-col staged MFMA GEMM, fp32 [K][N] weights, split-K ----------------
// (round-11 proven) 512 threads / 8 waves: wave = (M-half mh) x (col-group cg).
template<int CH>
__launch_bounds__(512)
__global__ void gemm64_kernel(const unsigned short* __restrict__ A, int lda,
                              const float* __restrict__ W0, const float* __restrict__ W1,
                              const float* __restrict__ W2, int ldw,
                              float* __restrict__ out, int ldo, int zColOff,
                              size_t chunkStride) {
    constexpr int STAGES = CH / 128;
    constexpr int LSTR = 136;
    __shared__ unsigned short Bst[2][64 * LSTR];
    const float* W = blockIdx.z == 0 ? W0 : (blockIdx.z == 1 ? W1 : W2);
    const int tid = threadIdx.x;
    const int wave = tid >> 6, lane = tid & 63;
    const int cg = wave & 3, mh = wave >> 2;
    const int n0 = blockIdx.x * 64;
    const int k0 = blockIdx.y * CH;
    const int sc = tid & 63;
    const int so = tid >> 6;  // 0..7
    const float* wCol = W + (size_t)k0 * ldw + n0 + sc;
    unsigned short* wp = &Bst[0][sc * LSTR];
    const int lrow = lane & 15;
    const int lqo = lane >> 4;
    const unsigned short* aB = A + (size_t)(mh * 64 + lrow) * lda + k0 + lqo * 8;
    const unsigned short* bRd = &Bst[0][(cg * 16 + lrow) * LSTR + lqo * 8];
    f32x4 acc[4] = {};
    float pre[16];
    auto ldst = [&](int s) {
        #pragma unroll
        for (int p = 0; p < 2; ++p) {
            const float* src = wCol + (size_t)(s * 128 + (so * 2 + p) * 8) * ldw;
            #pragma unroll
            for (int j = 0; j < 8; ++j) pre[p * 8 + j] = src[(size_t)j * ldw];
        }
    };
    auto wrst = [&](int buf) {
        #pragma unroll
        for (int p = 0; p < 2; ++p) {
            short8 bv;
            #pragma unroll
            for (int j = 0; j < 8; ++j) bv[j] = (short)f2bf(pre[p * 8 + j]);
            *(short8*)(wp + buf * (64 * LSTR) + (so * 2 + p) * 8) = bv;
        }
    };
    ldst(0);
    wrst(0);
    __syncthreads();
    #pragma unroll
    for (int s = 0; s < STAGES; ++s) {
        if (s + 1 < STAGES) ldst(s + 1);
        const unsigned short* rd = bRd + (s & 1) * (64 * LSTR);
        #pragma unroll
        for (int ks = 0; ks < 4; ++ks) {
            short8 b = *(const short8*)(rd + ks * 32);
            #pragma unroll
            for (int mf = 0; mf < 4; ++mf) {
                short8 a = *(const short8*)(aB + (size_t)(mf * 16) * lda + s * 128 + ks * 32);
                acc[mf] = __builtin_amdgcn_mfma_f32_16x16x32_bf16(a, b, acc[mf], 0, 0, 0);
            }
        }
        if (s + 1 < STAGES) {
            __syncthreads();
            wrst((s + 1) & 1);
            __syncthreads();
        }
    }
    const int col = zColOff * blockIdx.z + n0 + cg * 16 + lrow;
    float* op = out + blockIdx.y * chunkStride;
    #pragma unroll
    for (int mf = 0; mf < 4; ++mf) {
        int r0 = mh * 64 + mf * 16 + lqo * 4;
        #pragma unroll
        for (int r = 0; r < 4; ++r)
            op[(size_t)(r0 + r) * ldo + col] = acc[mf][r];
    }
}

// ---------------- QKV partial reduce + RoPE -> Qr,Vr [T][D]; K TRANSPOSED [H][DH][T] ----
__launch_bounds__(256)
__global__ void rope_reduce_kernel(const float* __restrict__ P,
                                   const float* __restrict__ cosT, const float* __restrict__ sinT,
                                   float* __restrict__ Qr, float* __restrict__ KrT,
                                   float* __restrict__ Vr) {
    int t = blockIdx.x, tid = threadIdx.x;
    int d0 = tid * 4;
    float4 q = {0.f, 0.f, 0.f, 0.f}, k = q, v = q;
    #pragma unroll
    for (int c = 0; c < NP_Q; ++c) {
        const float* base = P + ((size_t)c * T + t) * QKVN;
        float4 a = ((const float4*)base)[tid];
        float4 b = ((const float4*)(base + D))[tid];
        float4 w = ((const float4*)(base + 2 * D))[tid];
        q.x += a.x; q.y += a.y; q.z += a.z; q.w += a.w;
        k.x += b.x; k.y += b.y; k.z += b.z; k.w += b.w;
        v.x += w.x; v.y += w.y; v.z += w.z; v.w += w.w;
    }
    float4 c4 = *(const float4*)(cosT + t * 32 + (d0 & 31));
    float4 s4 = *(const float4*)(sinT + t * 32 + (d0 & 31));
    float sgn = (d0 & 32) ? 1.f : -1.f;
    float4 qp, kp;
    qp.x = __shfl_xor(q.x, 8); qp.y = __shfl_xor(q.y, 8);
    qp.z = __shfl_xor(q.z, 8); qp.w = __shfl_xor(q.w, 8);
    kp.x = __shfl_xor(k.x, 8); kp.y = __shfl_xor(k.y, 8);
    kp.z = __shfl_xor(k.z, 8); kp.w = __shfl_xor(k.w, 8);
    float4 qo, ko;
    qo.x = q.x * c4.x + sgn * qp.x * s4.x; qo.y = q.y * c4.y + sgn * qp.y * s4.y;
    qo.z = q.z * c4.z + sgn * qp.z * s4.z; qo.w = q.w * c4.w + sgn * qp.w * s4.w;
    ko.x = k.x * c4.x + sgn * kp.x * s4.x; ko.y = k.y * c4.y + sgn * kp.y * s4.y;
    ko.z = k.z * c4.z + sgn * kp.z * s4.z; ko.w = k.w * c4.w + sgn * kp.w * s4.w;
    *(float4*)(Qr + (size_t)t * D + d0) = qo;
    *(float4*)(Vr + (size_t)t * D + d0) = v;
    // K transposed: KrT[d][t], d global in [0,D)  (== [h][dh][t] since D = H*DH)
    KrT[(size_t)(d0 + 0) * T + t] = ko.x;
    KrT[(size_t)(d0 + 1) * T + t] = ko.y;
    KrT[(size_t)(d0 + 2) * T + t] = ko.z;
    KrT[(size_t)(d0 + 3) * T + t] = ko.w;
}

// ---------------- Causal attention: 4 heads/block, coalesced K^T scores ----------------
__launch_bounds__(256)
__global__ void attn_kernel(const float* __restrict__ Q, const float* __restrict__ KrT,
                            const float* __restrict__ Vc, unsigned short* __restrict__ AO) {
    int t = blockIdx.x;
    int wave = threadIdx.x >> 6, lane = threadIdx.x & 63;
    int h = blockIdx.y * 4 + wave;
    __shared__ float qs[4][64];
    __shared__ float ps[4][128];
    float* q = qs[wave];
    float* p = ps[wave];
    q[lane] = Q[(size_t)t * D + h * DH + lane];
    __syncthreads();
    // scores: lane = key j0 (and j1 = lane+64); K^T rows are lane-consecutive
    int j0 = lane, j1 = lane + 64;
    const float* kr = KrT + (size_t)h * DH * T;
    float s0 = 0.f, s1 = 0.f;
    #pragma unroll
    for (int d = 0; d < DH; ++d) {
        float qd = q[d];
        const float* krow = kr + (size_t)d * T;
        s0 = fmaf(qd, krow[j0], s0);
        s1 = fmaf(qd, krow[j1], s1);
    }
    s0 = (j0 <= t) ? s0 * SCALE : -1e30f;
    s1 = (j1 <= t) ? s1 * SCALE : -1e30f;
    float m = fmaxf(s0, s1);
    for (int o = 32; o >= 1; o >>= 1) m = fmaxf(m, __shfl_xor(m, o));
    float e0 = (j0 <= t) ? __expf(s0 - m) : 0.f;
    float e1 = (j1 <= t) ? __expf(s1 - m) : 0.f;
    float sum = e0 + e1;
    for (int o = 32; o >= 1; o >>= 1) sum += __shfl_xor(sum, o);
    float inv = 1.f / sum;
    p[j0] = e0 * inv;   // p[j] = 0 for j > t -> fixed-trip PV exact
    p[j1] = e1 * inv;
    __syncthreads();
    const float* vcol = Vc + h * DH + lane;
    float a0 = 0.f, a1 = 0.f, a2 = 0.f, a3 = 0.f;
    #pragma unroll
    for (int j = 0; j < T; j += 4) {
        a0 = fmaf(p[j],     vcol[(size_t)(j)     * D], a0);
        a1 = fmaf(p[j + 1], vcol[(size_t)(j + 1) * D], a1);
        a2 = fmaf(p[j + 2], vcol[(size_t)(j + 2) * D], a2);
        a3 = fmaf(p[j + 3], vcol[(size_t)(j + 3) * D], a3);
    }
    AO[(size_t)t * D + h * DH + lane] = f2bf((a0 + a1) + (a2 + a3));
}

// ---------------- GU partial reduce + silu(g)*u -> Gact bf16 [T][F] ----------------
__launch_bounds__(256)
__global__ void silu_reduce_kernel(const float* __restrict__ P,
                                   unsigned short* __restrict__ Gact) {
    int t = blockIdx.y;
    int f = blockIdx.x * 256 + threadIdx.x;
    float g = 0.f, u = 0.f;
    #pragma unroll
    for (int c = 0; c < NP_G; ++c) {
        const float* base = P + ((size_t)c * T + t) * GUN;
        g += base[f];
        u += base[F + f];
    }
    Gact[(size_t)t * F + f] = f2bf(g / (1.f + __expf(-g)) * u);
}

// ---------------- logits: out[v] = emb[v,:] . xl ----------------
__global__ void logits_kernel(const float* __restrict__ emb, const float* __restrict__ xl,
                              float* __restrict__ out) {
    __shared__ float x[D];
    int tid = threadIdx.x;
    ((float4*)x)[tid] = ((const float4*)xl)[tid];
    __syncthreads();
    int row = blockIdx.x * 4 + (tid >> 6);
    int lane = tid & 63;
    const float4* e4 = (const float4*)(emb + (size_t)row * D);
    const float4* x4 = (const float4*)x;
    float s = 0.f;
    #pragma unroll
    for (int k = lane; k < D / 4; k += 64) {
        float4 ev = e4[k], xv = x4[k];
        s += ev.x * xv.x + ev.y * xv.y + ev.z * xv.z + ev.w * xv.w;
    }
    for (int o = 32; o >= 1; o >>= 1) s += __shfl_xor(s, o);
    if (lane == 0) out[row] = s;
}

extern "C" void kernel_launch(void* const* d_in, const int* in_sizes, int n_in,
                              void* d_out, int out_size, void* d_ws, size_t ws_size,
                              hipStream_t stream) {
    const int*   ids = (const int*)d_in[0];
    const float* emb = (const float*)d_in[1];
    const float* Wq  = (const float*)d_in[2];
    const float* Wk  = (const float*)d_in[3];
    const float* Wv  = (const float*)d_in[4];
    const float* Wo  = (const float*)d_in[5];
    const float* Wg  = (const float*)d_in[6];
    const float* Wu  = (const float*)d_in[7];
    const float* Wd  = (const float*)d_in[8];
    const float* attn_norm = (const float*)d_in[9];
    const float* ffn_norm  = (const float*)d_in[10];
    const float* norm_out  = (const float*)d_in[11];
    float* out = (float*)d_out;

    size_t off = 0;
    auto alloc = [&](size_t bytes) {
        void* p = (char*)d_ws + off;
        off += (bytes + 255) & ~(size_t)255;
        return p;
    };
    float*          X     = (float*)alloc((size_t)T * D * 4);
    float*          P0    = (float*)alloc((size_t)NP_Q * T * QKVN * 4);  // QKV partials
    float*          P1    = (float*)alloc((size_t)NP_O * T * D * 4);     // O-proj partials
    float*          P2    = (float*)alloc((size_t)NP_D * T * D * 4);     // Wd partials
    float*          P3    = (float*)alloc((size_t)NP_G * T * GUN * 4);   // GU partials
    float*          Qr    = (float*)alloc((size_t)T * D * 4);
    float*          KrT   = (float*)alloc((size_t)T * D * 4);
    float*          Vr    = (float*)alloc((size_t)T * D * 4);
    float*          cosT  = (float*)alloc((size_t)T * 32 * 4);
    float*          sinT  = (float*)alloc((size_t)T * 32 * 4);
    float*          xl    = (float*)alloc((size_t)D * 4);
    unsigned short* Hn_bf = (unsigned short*)alloc((size_t)T * D * 2);
    unsigned short* AO_bf = (unsigned short*)alloc((size_t)T * D * 2);
    unsigned short* Gact  = (unsigned short*)alloc((size_t)T * F * 2);
    (void)ws_size;

    embed_rope_kernel<<<T, 256, 0, stream>>>(ids, emb, X, cosT, sinT);

    for (int l = 0; l < L; ++l) {
        const float* wq = Wq + (size_t)l * D * D;
        const float* wk = Wk + (size_t)l * D * D;
        const float* wv = Wv + (size_t)l * D * D;
        const float* wo = Wo + (size_t)l * D * D;
        const float* wg = Wg + (size_t)l * D * F;
        const float* wu = Wu + (size_t)l * D * F;
        const float* wd = Wd + (size_t)l * F * D;

        // X += prev Wd partials; Hn = rmsnorm(X)*attn_norm (bf16)
        if (l == 0)
            rmsnorm_sum_kernel<0, true><<<T, 256, 0, stream>>>(
                X, P2, attn_norm + (size_t)l * D, Hn_bf);
        else
            rmsnorm_sum_kernel<NP_D, true><<<T, 256, 0, stream>>>(
                X, P2, attn_norm + (size_t)l * D, Hn_bf);
        // QKV partials: 64-col, K=1024 split 8x128, z in {q,k,v} -> 384 blocks x 8 waves
        gemm64_kernel<128><<<dim3(D / 64, NP_Q, 3), 512, 0, stream>>>(
            Hn_bf, D, wq, wk, wv, D, P0, QKVN, D, (size_t)T * QKVN);
        rope_reduce_kernel<<<T, 256, 0, stream>>>(P0, cosT, sinT, Qr, KrT, Vr);
        // attention: 4 heads/block, K^T coalesced scores, fixed-trip PV -> 512 blocks
        attn_kernel<<<dim3(T, H / 4), 256, 0, stream>>>(Qr, KrT, Vr, AO_bf);
        // O-proj partials: K=1024 split 8x128 -> 128 blocks x 8 waves
        gemm64_kernel<128><<<dim3(D / 64, NP_O, 1), 512, 0, stream>>>(
            AO_bf, D, wo, wo, wo, D, P1, D, 0, (size_t)T * D);
        rmsnorm_sum_kernel<NP_O, true><<<T, 256, 0, stream>>>(
            X, P1, ffn_norm + (size_t)l * D, Hn_bf);
        // GU partials: K=1024 split 8x128, z in {g,u} -> 704 blocks x 8 waves
        gemm64_kernel<128><<<dim3(F / 64, NP_G, 2), 512, 0, stream>>>(
            Hn_bf, D, wg, wu, wu, F, P3, GUN, F, (size_t)T * GUN);
        silu_reduce_kernel<<<dim3(F / 256, T), 256, 0, stream>>>(P3, Gact);
        // Wd partials: K=2816 split 22x128 -> 352 blocks x 8 waves
        gemm64_kernel<128><<<dim3(D / 64, NP_D, 1), 512, 0, stream>>>(
            Gact, F, wd, wd, wd, D, P2, D, 0, (size_t)T * D);
    }

    // final: xl = rmsnorm(X[127] + sum P2[c][127]) * norm_out (fp32)
    rmsnorm_sum_kernel<NP_D, false><<<1, 256, 0, stream>>>(
        X + (size_t)(T - 1) * D, P2 + (size_t)(T - 1) * D, norm_out, xl);
    logits_kernel<<<V / 4, 256, 0, stream>>>(emb, xl, out);
}